// Round 11
// baseline (321.921 us; speedup 1.0000x reference)
//
#include <hip/hip_runtime.h>

// ===== R11: 1KB-per-store-instruction test (LDS-staged cooperative stores),
// REPEAT=3 diagnostic =====
// Ledger: write rate tracks BYTES PER STORE INSTRUCTION monotonically:
// 128B/instr -> 3.78 TB/s (R8), 256-512B -> 4.78 (R1/R5/R7/R9/R10),
// fill's 64-lane 1KB dwordx4 -> 6.98. All scheduling variables exonerated
// (sync style, occupancy, balance, phase, barrier position). This round:
// per step, owning q-groups write the 16 fresh rows into an 8KB LDS slab;
// barrier; all 256 threads store the slab flat -> every global store is
// 64 lanes x 16B = 1KB contiguous (fill's exact instruction pattern).
// Stencil core unchanged: full-d blocks, QG=8 x K=15 = 120-row window,
// T=16 owned, halo 52 >= 51 needed; per-step board exchange in LDS.

namespace {

typedef float f4 __attribute__((ext_vector_type(4)));

constexpr int   REPEAT = 3;     // diagnostic replication (drop when tuned)
constexpr int   B      = 8;
constexpr int   N      = 2048;
constexpr int   D4     = 32;    // 128 floats = 32 f4 per row
constexpr int   STEPS  = 50;
constexpr float ALPHA  = 0.1f;
constexpr int   T      = 16;    // owned rows per block
constexpr int   QG     = 8;     // q-groups (256 thr / 32 lanes)
constexpr int   K      = 15;    // rows per thread
constexpr int   WIN    = QG * K;        // 120 window rows
constexpr int   HALO   = (WIN - T) / 2; // 52 >= 51 needed
constexpr int   CHUNKS = N / T;         // 128

__device__ __forceinline__ f4 stencil(const f4 p, const f4 c, const f4 n) {
    return c + ALPHA * (p + n - 2.0f * c);
}

__global__ __launch_bounds__(QG * D4, 4) void diffusion_stage(
        const f4* __restrict__ in4, f4* __restrict__ out4) {
    const int tid = threadIdx.x;
    const int d4  = tid & (D4 - 1);   // f4 lane along d (full row)
    const int q   = tid >> 5;         // row-group 0..7

    const int bid = blockIdx.x;
    const int c   = bid & (CHUNKS - 1);
    const int b   = bid >> 7;         // 1024 blocks / 128 chunks
    const int n0  = c * T;

    // Double-buffered boundary board (16 KB) + output slab (8 KB).
    __shared__ f4 lo[2][QG][D4];
    __shared__ f4 hi[2][QG][D4];
    __shared__ f4 slab[T][D4];

    const int rbase = q * K;

    for (int rep = 0; rep < REPEAT; ++rep) {
        f4 s[K];
        // Load window rows with wraparound (all real rows -> valid at t=0).
#pragma unroll
        for (int i = 0; i < K; ++i) {
            const int ng = (n0 + rbase + i - HALO + 2 * N) & (N - 1);
            s[i] = in4[(b * N + ng) * D4 + d4];
        }

        // out[0] = initial state (one-time; 2% of traffic, direct stores).
#pragma unroll
        for (int i = 0; i < K; ++i) {
            const int r = rbase + i - HALO;
            if (r >= 0 && r < T) {
                __builtin_nontemporal_store(
                    s[i], &out4[(b * N + (n0 + r)) * D4 + d4]);
            }
        }

        for (int k = 1; k <= STEPS; ++k) {
            const int buf = k & 1;
            // (1) Publish old boundary rows; one barrier (double-buffered).
            lo[buf][q][d4] = s[0];
            hi[buf][q][d4] = s[K - 1];
            asm volatile("s_waitcnt lgkmcnt(0)" ::: "memory");
            __builtin_amdgcn_s_barrier();
            const f4 bl = (q > 0)      ? hi[buf][q - 1][d4] : (f4)(0.f);
            const f4 bh = (q < QG - 1) ? lo[buf][q + 1][d4] : (f4)(0.f);

            // (2) In-register stencil; owned rows go to the LDS slab.
            f4 prev = bl;
#pragma unroll
            for (int i = 0; i < K; ++i) {
                const f4 cur = s[i];
                const f4 nxt = (i + 1 < K) ? s[i + 1] : bh;
                s[i] = stencil(prev, cur, nxt);
                prev = cur;
                const int r = rbase + i - HALO;
                if (r >= 0 && r < T) slab[r][d4] = s[i];
            }

            // (3) Slab ready -> cooperative 1KB-per-instruction stores.
            asm volatile("s_waitcnt lgkmcnt(0)" ::: "memory");
            __builtin_amdgcn_s_barrier();
            {
                const f4* sl = &slab[0][0];
                const int base = ((k * B + b) * N + n0) * D4;
                __builtin_nontemporal_store(sl[tid], &out4[base + tid]);
                __builtin_nontemporal_store(sl[256 + tid],
                                            &out4[base + 256 + tid]);
            }
            // Slab-reuse safety: next step's slab writes occur after the
            // next barrier(1); every thread drains its own ds_reads at its
            // lgkmcnt(0) before signaling that barrier, so no write can
            // land before all reads completed. Board reuse: two-step gap
            // with an intervening lgkmcnt(0)+barrier, as in R5.
        }
    }
}

}  // namespace

extern "C" void kernel_launch(void* const* d_in, const int* in_sizes, int n_in,
                              void* d_out, int out_size, void* d_ws, size_t ws_size,
                              hipStream_t stream) {
    const f4* in4  = reinterpret_cast<const f4*>(d_in[0]);
    f4*       out4 = reinterpret_cast<f4*>(d_out);

    dim3 grid(B * CHUNKS);   // 1024 blocks -> 4 per CU
    dim3 block(QG * D4);     // 256 threads
    diffusion_stage<<<grid, block, 0, stream>>>(in4, out4);
}

// Round 12
// 246.266 us; speedup vs baseline: 1.3072x; 1.3072x over previous
//
#include <hip/hip_runtime.h>

// ===== R12: producer/consumer wave specialization, REPEAT=3 diagnostic =====
// Ledger: write rate ~4.8 TB/s invariant under sync style, occupancy, store
// balance, phase stagger, barrier position, and store-instruction shape
// (R11: 1KB/instr -> falsified). Surviving theory: the storing waves
// periodically stop issuing (compute+exchange window); fair backpressure
// re-syncs all waves -> chip-wide store-silent gaps every step. Fix: role
// split. 4 producer waves stencil in registers and deposit owned rows into
// a depth-2 LDS ring (16KB/slot); 4 consumer waves drain the opposite slot
// with 1KB nontemporal stores, issuing continuously across the whole step
// while producers compute. One barrier/step hands off slots.
// Geometry (R1): full-d rows, 8 groups x 32 lanes, K=17, window 136, T=32,
// halo 52 >= 50. Grid 512 blocks x 512 thr (2 blocks/CU, 16 waves/CU).

namespace {

typedef float f4 __attribute__((ext_vector_type(4)));

constexpr int   REPEAT = 3;     // diagnostic replication (drop when tuned)
constexpr int   B      = 8;
constexpr int   N      = 2048;
constexpr int   D4     = 32;    // 128 floats = 32 f4 per row
constexpr int   STEPS  = 50;
constexpr float ALPHA  = 0.1f;
constexpr int   T      = 32;    // owned rows per block
constexpr int   QG     = 8;     // producer row-groups (256 thr / 32 lanes)
constexpr int   K      = 17;    // rows per producer thread
constexpr int   WIN    = QG * K;        // 136 window rows
constexpr int   HALO   = (WIN - T) / 2; // 52 >= 50
constexpr int   CHUNKS = N / T;         // 64

__device__ __forceinline__ f4 stencil(const f4 p, const f4 c, const f4 n) {
    return c + ALPHA * (p + n - 2.0f * c);
}

__global__ __launch_bounds__(512, 1) void diffusion_pc(
        const f4* __restrict__ in4, f4* __restrict__ out4) {
    const int tid = threadIdx.x;
    const int bid = blockIdx.x;
    const int c   = bid & (CHUNKS - 1);
    const int b   = bid >> 6;
    const int n0  = c * T;

    // Producer-side ids (tid < 256): full row, 8 groups x 32 lanes.
    const int d4 = tid & (D4 - 1);
    const int q  = (tid >> 5) & (QG - 1);
    const int rbase = q * K;
    const bool producer = (tid < 256);

    // Consumer-side ids (tid >= 256): flat drain index.
    const int ctid = tid & 255;

    __shared__ f4 lo[2][QG][D4];      // 8 KB
    __shared__ f4 hi[2][QG][D4];      // 8 KB
    __shared__ f4 ring[2][T * D4];    // 2 x 16 KB

    for (int rep = 0; rep < REPEAT; ++rep) {
        f4 s[K];
        if (producer) {
            // Load window rows with wraparound (all real -> valid at t=0).
#pragma unroll
            for (int i = 0; i < K; ++i) {
                const int ng = (n0 + rbase + i - HALO + 2 * N) & (N - 1);
                s[i] = in4[(b * N + ng) * D4 + d4];
            }
            // out[0] = initial state (2% of traffic, direct).
#pragma unroll
            for (int i = 0; i < K; ++i) {
                const int r = rbase + i - HALO;
                if (r >= 0 && r < T) {
                    __builtin_nontemporal_store(
                        s[i], &out4[(b * N + (n0 + r)) * D4 + d4]);
                }
            }
        }

        for (int k = 1; k <= STEPS; ++k) {
            const int buf = k & 1;
            if (producer) {
                // Publish old boundary rows of this group.
                lo[buf][q][d4] = s[0];
                hi[buf][q][d4] = s[K - 1];
            }
            // Orders: board publish (this step), ring writes (prev step),
            // consumer ds_reads (prev slot, already drained to VGPRs).
            asm volatile("s_waitcnt lgkmcnt(0)" ::: "memory");
            __builtin_amdgcn_s_barrier();

            if (producer) {
                const f4 bl = (q > 0)      ? hi[buf][q - 1][d4] : (f4)(0.f);
                const f4 bh = (q < QG - 1) ? lo[buf][q + 1][d4] : (f4)(0.f);
                // In-register carry-chain stencil; owned rows -> ring slot.
                f4 prev = bl;
#pragma unroll
                for (int i = 0; i < K; ++i) {
                    const f4 cur = s[i];
                    const f4 nxt = (i + 1 < K) ? s[i + 1] : bh;
                    s[i] = stencil(prev, cur, nxt);
                    prev = cur;
                    const int r = rbase + i - HALO;
                    if (r >= 0 && r < T) {
                        ring[buf][(r << 5) + d4] = s[i];
                    }
                }
            } else if (k >= 2) {
                // Drain slot (k-1)&1 = buf^1 -> out step k-1, while
                // producers compute step k. 4 x 1KB nt stores per wave.
                const f4* sl = ring[buf ^ 1];
                const int base = (((k - 1) * B + b) * N + n0) * D4;
#pragma unroll
                for (int m = 0; m < 4; ++m) {
                    const int j = ctid + (m << 8);
                    __builtin_nontemporal_store(sl[j], &out4[base + j]);
                }
            }
        }

        // Final drain: slot STEPS&1 -> out step 50.
        asm volatile("s_waitcnt lgkmcnt(0)" ::: "memory");
        __builtin_amdgcn_s_barrier();
        if (!producer) {
            const f4* sl = ring[STEPS & 1];
            const int base = ((STEPS * B + b) * N + n0) * D4;
#pragma unroll
            for (int m = 0; m < 4; ++m) {
                const int j = ctid + (m << 8);
                __builtin_nontemporal_store(sl[j], &out4[base + j]);
            }
        }
        // Protect ring/board reuse across reps.
        __builtin_amdgcn_s_barrier();
    }
}

}  // namespace

extern "C" void kernel_launch(void* const* d_in, const int* in_sizes, int n_in,
                              void* d_out, int out_size, void* d_ws, size_t ws_size,
                              hipStream_t stream) {
    const f4* in4  = reinterpret_cast<const f4*>(d_in[0]);
    f4*       out4 = reinterpret_cast<f4*>(d_out);

    dim3 grid(B * CHUNKS);   // 512 blocks -> 2 per CU
    dim3 block(512);         // 4 producer + 4 consumer waves
    diffusion_pc<<<grid, block, 0, stream>>>(in4, out4);
}